// Round 19
// baseline (684.069 us; speedup 1.0000x reference)
//
#include <hip/hip_runtime.h>
#include <hip/hip_bf16.h>
#include <math.h>

#define LLc  4
#define BBc  2
#define SSc  2048
#define FFc  256
#define HHc  8
#define DKc  32
#define MMc  10
#define HDKc 256
#define F4c  1024
#define NRc  4096          /* B*S */
#define ISQD 0.17677669529663687f  /* 1/sqrt(32) */
#define LOG2E 1.4426950408889634f
#define ZSP  4             /* j-split */
#define BHS  32768         /* B*H*S */

typedef unsigned short u16;
typedef unsigned char  u8;
typedef unsigned int   u32;
typedef __attribute__((ext_vector_type(8))) short short8;
typedef __attribute__((ext_vector_type(4))) float f32x4;

__device__ __forceinline__ u16 f2bf(float f) {
    u32 x; __builtin_memcpy(&x, &f, 4);
    x += 0x7FFFu + ((x >> 16) & 1u);
    return (u16)(x >> 16);
}
__device__ __forceinline__ float bf2f(u16 u) {
    u32 x = ((u32)u) << 16; float f; __builtin_memcpy(&f, &x, 4); return f;
}

__global__ __launch_bounds__(256)
void fill_f32(float* __restrict__ p, float v) {
    p[(size_t)blockIdx.x * 256 + threadIdx.x] = v;
}

// ---------------- rel index table: rel8[b][i][j], u8, layer-invariant ----------------
__global__ __launch_bounds__(256)
void build_rel8(const int* __restrict__ pos, u8* __restrict__ rel8)
{
    const int id = blockIdx.x * 256 + threadIdx.x;      // B*S*S/4
    const int j4 = id & (SSc / 4 - 1);
    const int i  = (id >> 9) & (SSc - 1);
    const int b  = id >> 20;
    const int pi = pos[b * SSc + i];
    uchar4 o;
    u8* po = (u8*)&o;
#pragma unroll
    for (int t = 0; t < 4; ++t) {
        const int pj = pos[b * SSc + j4 * 4 + t];
        int dd = pi - pj; if (dd < 0) dd = -dd;
        int ridx = dd;
        if (dd > MMc) {
            int v = (int)(10.0f + __log2f((float)(dd - MMc)));
            ridx = v > 2 * MMc ? 2 * MMc : v;
        }
        po[t] = (u8)ridx;
    }
    *(uchar4*)&rel8[(size_t)id * 4] = o;
}

// ---------------- fused QKV GEMM: grid (4, 64, 3); z: 0=Q 1=K 2=V ---------------------
template<bool LNA>
__global__ __launch_bounds__(256)
void qkv_mfma(const float* __restrict__ A,
              const float* __restrict__ PartIn,
              const float* __restrict__ lng, const float* __restrict__ lnb,
              const float* __restrict__ Wq, const float* __restrict__ bq_,
              const float* __restrict__ Wk, const float* __restrict__ bk_,
              const float* __restrict__ Wv, const float* __restrict__ bv_,
              u16* __restrict__ Qbf, u16* __restrict__ Kbf, u16* __restrict__ Vbf)
{
    __shared__ u16 As[64][40];
    __shared__ u16 Bt[64][40];
    const int tid = threadIdx.x;
    const int w = tid >> 6, lane = tid & 63;
    const int g = lane >> 4, c = lane & 15;
    const int i0 = blockIdx.y * 64, n0 = blockIdx.x * 64;
    const int srow = tid & 63, sk8 = (tid >> 6) * 8;

    const float* W; const float* bias; u16* Out; float scale;
    if (blockIdx.z == 0)      { W = Wq; bias = bq_; Out = Qbf; scale = ISQD; }
    else if (blockIdx.z == 1) { W = Wk; bias = bk_; Out = Kbf; scale = 1.0f; }
    else                      { W = Wv; bias = bv_; Out = Vbf; scale = 1.0f; }

    float mu = 0.f, iv = 0.f;
    if (LNA) {
        const float* pp = PartIn + (size_t)(i0 + srow) * 16;
        float ls = 0.f, ss = 0.f;
#pragma unroll
        for (int t = 0; t < 8; ++t) { ls += pp[t * 2]; ss += pp[t * 2 + 1]; }
        mu = ls * (1.0f / FFc);
        float var = ss * (1.0f / FFc) - mu * mu;
        var = fmaxf(var, 0.0f);
        iv = 1.0f / sqrtf(var + 1e-5f);
    }

    f32x4 acc[4] = {{0.f,0.f,0.f,0.f},{0.f,0.f,0.f,0.f},{0.f,0.f,0.f,0.f},{0.f,0.f,0.f,0.f}};

    for (int k0 = 0; k0 < FFc; k0 += 32) {
        __syncthreads();
        {
            const float* ap = A + (size_t)(i0 + srow) * FFc + k0 + sk8;
            float v[8];
            *(float4*)&v[0] = *(const float4*)&ap[0];
            *(float4*)&v[4] = *(const float4*)&ap[4];
            if (LNA) {
#pragma unroll
                for (int t = 0; t < 8; ++t)
                    v[t] = (v[t] - mu) * iv * lng[k0 + sk8 + t] + lnb[k0 + sk8 + t];
            }
            short8 st;
#pragma unroll
            for (int t = 0; t < 8; ++t) st[t] = (short)f2bf(v[t]);
            *(short8*)&As[srow][sk8] = st;
        }
        {
            const float* wp = W + (size_t)(k0 + sk8) * HDKc + n0 + srow;
            short8 st;
#pragma unroll
            for (int t = 0; t < 8; ++t) st[t] = (short)f2bf(wp[(size_t)t * HDKc]);
            *(short8*)&Bt[srow][sk8] = st;
        }
        __syncthreads();
        const short8 af = *(const short8*)&As[w * 16 + c][g * 8];
#pragma unroll
        for (int nt = 0; nt < 4; ++nt) {
            const short8 bf = *(const short8*)&Bt[nt * 16 + c][g * 8];
            acc[nt] = __builtin_amdgcn_mfma_f32_16x16x32_bf16(af, bf, acc[nt], 0, 0, 0);
        }
    }

#pragma unroll
    for (int nt = 0; nt < 4; ++nt) {
        const int col = n0 + nt * 16 + c;
        const float bsv = bias[col];
#pragma unroll
        for (int r = 0; r < 4; ++r) {
            const int row = i0 + w * 16 + g * 4 + r;
            const int b = row >> 11, s = row & (SSc - 1);
            const int h = col >> 5, d = col & 31;
            Out[((size_t)(b * HHc + h) * SSc + s) * DKc + d] = f2bf((acc[nt][r] + bsv) * scale);
        }
    }
}

// ---------------- generic bf16-MFMA GEMM -----------------------------------------------
// MODE 0: f32 out. MODE 3: GELU -> bf16 out. NSUM slabs summed. LNA: LN on A (f32 A),
// stats from PartIn. ABF: A bf16. LSC: scale A by 1/sum_z Lpart (inline). EMITPS: emit
// per-block row partial (sum, sumsq) into PartOut[row][8][2] (NT==2 producers only).
template<int MODE, int NSUM, bool LNA, bool ABF, int NT, bool LSC, bool EMITPS>
__global__ __launch_bounds__(256)
void gemm_mfma(const void* __restrict__ Aptr, size_t Astride,
               const float* __restrict__ PartIn, float* __restrict__ PartOut,
               const float* __restrict__ lng, const float* __restrict__ lnb,
               const float* __restrict__ Lpart,
               const float* __restrict__ W, const float* __restrict__ bias,
               float* __restrict__ C, u16* __restrict__ Cb, int Nc, int Kd)
{
    __shared__ u16 As[64][40];
    __shared__ u16 Bt[NT * 16][40];
    const int tid = threadIdx.x;
    const int w = tid >> 6, lane = tid & 63;
    const int g = lane >> 4, c = lane & 15;
    const int i0 = blockIdx.y * 64, n0 = blockIdx.x * (NT * 16);
    const int srow = tid & 63, sk8 = (tid >> 6) * 8;

    float mu = 0.f, iv = 0.f;
    if (LNA) {
        const float* pp = PartIn + (size_t)(i0 + srow) * 16;
        float ls = 0.f, ss = 0.f;
#pragma unroll
        for (int t = 0; t < 8; ++t) { ls += pp[t * 2]; ss += pp[t * 2 + 1]; }
        mu = ls * (1.0f / FFc);
        float var = ss * (1.0f / FFc) - mu * mu;
        var = fmaxf(var, 0.0f);
        iv = 1.0f / sqrtf(var + 1e-5f);
    }

    f32x4 acc[NT];
#pragma unroll
    for (int nt = 0; nt < NT; ++nt) acc[nt] = (f32x4){0.f, 0.f, 0.f, 0.f};

    for (int k0 = 0; k0 < Kd; k0 += 32) {
        __syncthreads();
        if (ABF) {
            const u16* ap = (const u16*)Aptr + (size_t)(i0 + srow) * Kd + k0 + sk8;
            if (NSUM == 1 && !LSC) {
                *(short8*)&As[srow][sk8] = *(const short8*)ap;
            } else {
                float v[8];
                const short8 s0 = *(const short8*)ap;
#pragma unroll
                for (int e = 0; e < 8; ++e) v[e] = bf2f((u16)s0[e]);
#pragma unroll
                for (int t = 1; t < NSUM; ++t) {
                    const short8 st = *(const short8*)(ap + (size_t)t * Astride);
#pragma unroll
                    for (int e = 0; e < 8; ++e) v[e] += bf2f((u16)st[e]);
                }
                if (LSC) {
                    const int row = i0 + srow;
                    const int h = (k0 + sk8) >> 5;
                    const int bhs = (((row >> 11) * HHc + h) * SSc) + (row & (SSc - 1));
                    float ls = 0.f;
#pragma unroll
                    for (int z = 0; z < ZSP; ++z) ls += Lpart[(size_t)z * BHS + bhs];
                    const float scl = 1.0f / ls;
#pragma unroll
                    for (int e = 0; e < 8; ++e) v[e] *= scl;
                }
                short8 so;
#pragma unroll
                for (int e = 0; e < 8; ++e) so[e] = (short)f2bf(v[e]);
                *(short8*)&As[srow][sk8] = so;
            }
        } else {
            const float* ap = (const float*)Aptr + (size_t)(i0 + srow) * Kd + k0 + sk8;
            float v[8];
            *(float4*)&v[0] = *(const float4*)&ap[0];
            *(float4*)&v[4] = *(const float4*)&ap[4];
            if (LNA) {
#pragma unroll
                for (int t = 0; t < 8; ++t)
                    v[t] = (v[t] - mu) * iv * lng[k0 + sk8 + t] + lnb[k0 + sk8 + t];
            }
            short8 st;
#pragma unroll
            for (int t = 0; t < 8; ++t) st[t] = (short)f2bf(v[t]);
            *(short8*)&As[srow][sk8] = st;
        }
        if (NT == 4) {
            const float* wp = W + (size_t)(k0 + sk8) * Nc + n0 + srow;
            short8 st;
#pragma unroll
            for (int t = 0; t < 8; ++t) st[t] = (short)f2bf(wp[(size_t)t * Nc]);
            *(short8*)&Bt[srow][sk8] = st;
        } else {  // NT == 2: 32 cols x 32 k, 4 elems/thread
            const int col = tid & 31, kb = (tid >> 5) * 4;
            const float* wp = W + (size_t)(k0 + kb) * Nc + n0 + col;
            ushort4 st;
            st.x = f2bf(wp[0]);
            st.y = f2bf(wp[(size_t)1 * Nc]);
            st.z = f2bf(wp[(size_t)2 * Nc]);
            st.w = f2bf(wp[(size_t)3 * Nc]);
            *(ushort4*)&Bt[col][kb] = st;
        }
        __syncthreads();
        const short8 af = *(const short8*)&As[w * 16 + c][g * 8];
#pragma unroll
        for (int nt = 0; nt < NT; ++nt) {
            const short8 bf = *(const short8*)&Bt[nt * 16 + c][g * 8];
            acc[nt] = __builtin_amdgcn_mfma_f32_16x16x32_bf16(af, bf, acc[nt], 0, 0, 0);
        }
    }

    float vv[NT][4];
#pragma unroll
    for (int nt = 0; nt < NT; ++nt) {
        const int col = n0 + nt * 16 + c;
        const float bsv = bias[col];
#pragma unroll
        for (int r = 0; r < 4; ++r) {
            float v = acc[nt][r] + bsv;
            vv[nt][r] = v;
            const int row = i0 + w * 16 + g * 4 + r;
            if (MODE == 3) {
                const float ge = 0.5f * v * (1.0f + erff(v * 0.70710678118654752f));
                Cb[(size_t)row * Nc + col] = f2bf(ge);
            } else {
                C[(size_t)row * Nc + col] = v;
            }
        }
    }
    if (EMITPS) {
#pragma unroll
        for (int r = 0; r < 4; ++r) {
            float s  = vv[0][r] + vv[1][r];
            float s2 = vv[0][r] * vv[0][r] + vv[1][r] * vv[1][r];
#pragma unroll
            for (int m = 1; m < 16; m <<= 1) { s += __shfl_xor(s, m, 16); s2 += __shfl_xor(s2, m, 16); }
            if (c == 0) {
                const int row = i0 + w * 16 + g * 4 + r;
                PartOut[(size_t)row * 16 + blockIdx.x * 2]     = s;
                PartOut[(size_t)row * 16 + blockIdx.x * 2 + 1] = s2;
            }
        }
    }
}

// ---------------- final LayerNorm -> f32 d_out x region -------------------------------
__global__ __launch_bounds__(256)
void ln_final(const float* __restrict__ Xi, const float* __restrict__ g,
              const float* __restrict__ bia, float* __restrict__ Yout)
{
    const int row = blockIdx.x * 4 + (threadIdx.x >> 6);
    const int lane = threadIdx.x & 63;
    const float4 v = *(const float4*)&Xi[(size_t)row * FFc + lane * 4];
    float s = v.x + v.y + v.z + v.w;
    float s2 = v.x * v.x + v.y * v.y + v.z * v.z + v.w * v.w;
#pragma unroll
    for (int m = 1; m < 64; m <<= 1) { s += __shfl_xor(s, m); s2 += __shfl_xor(s2, m); }
    const float mu = s * (1.0f / FFc);
    float var = s2 * (1.0f / FFc) - mu * mu;
    var = fmaxf(var, 0.0f);
    const float inv = 1.0f / sqrtf(var + 1e-5f);
    const float4 gv = *(const float4*)&g[lane * 4];
    const float4 bv = *(const float4*)&bia[lane * 4];
    float4 o;
    o.x = (v.x - mu) * inv * gv.x + bv.x;
    o.y = (v.y - mu) * inv * gv.y + bv.y;
    o.z = (v.z - mu) * inv * gv.z + bv.z;
    o.w = (v.w - mu) * inv * gv.w + bv.w;
    *(float4*)&Yout[(size_t)row * FFc + lane * 4] = o;
}

// ---------------- attention probs: UNNORMALIZED p -> PV; emits Lpart ------------------
// Corrected T14: V(t+1) load issued a full iteration early; scatter AFTER compute into
// the alternate buffer; ONE barrier per tile (race-free by barrier-skew argument).
__global__ __launch_bounds__(256)
void attn_probs(const u16* __restrict__ Qbf, const u16* __restrict__ Kbf,
                const u16* __restrict__ Vbf,
                const u8* __restrict__ rel8,
                const float* __restrict__ rk_t, const float* __restrict__ rb_t,
                float* __restrict__ Lpart,
                u16* __restrict__ OPartB)
{
    __shared__ u16 Vt[2][32 * 72];
    __shared__ u16 Pst[4][16 * 72];
    __shared__ float rks2[2 * MMc + 1], rbs2[2 * MMc + 1];

    const int tid = threadIdx.x;
    const int w = tid >> 6, lane = tid & 63;
    const int g = lane >> 4, c = lane & 15;
    const int bh = blockIdx.y, b = bh >> 3, h = bh & 7;
    const int z = blockIdx.z;
    const int iw = blockIdx.x * 64 + w * 16;

    if (tid < 2 * MMc + 1) {
        rks2[tid] = rk_t[tid * HHc + h] * LOG2E;
        rbs2[tid] = rb_t[tid * HHc + h] * LOG2E;
    }
    const short8 qf = *(const short8*)(Qbf + ((size_t)bh * SSc + iw + c) * DKc + g * 8);
    const u8* relrow = rel8 + ((size_t)b * SSc + iw + c) * SSc;
    const u16* Kbase = Kbf + (size_t)bh * SSc * DKc + g * 8;
    const int vj = tid >> 2, vseg = tid & 3, vd0 = vseg * 8;
    const u16* Vbase = Vbf + (size_t)bh * SSc * DKc + (size_t)vj * DKc + vseg * 8;

    const int jbeg = z * (SSc / ZSP);
    const int NTI = (SSc / ZSP) / 64;          // 8 tiles

    // prologue: V(0) -> Vt[0]; issue V(1) load
    {
        const short8 v0 = *(const short8*)(Vbase + (size_t)jbeg * DKc);
#pragma unroll
        for (int k = 0; k < 8; ++k) Vt[0][(vd0 + k) * 72 + vj] = (u16)v0[k];
    }
    short8 vnext = *(const short8*)(Vbase + (size_t)(jbeg + 64) * DKc);  // NTI>1 always
    __syncthreads();

    float lrun = 0.f;
    f32x4 Of[2] = {{0.f,0.f,0.f,0.f}, {0.f,0.f,0.f,0.f}};

    for (int t = 0; t < NTI; ++t) {
        const int j0 = jbeg + t * 64;
        const int buf = t & 1;

#pragma unroll
        for (int jg = 0; jg < 4; ++jg) {
            const short8 kf = *(const short8*)(Kbase + (size_t)(j0 + jg * 16 + c) * DKc);
            f32x4 sc = __builtin_amdgcn_mfma_f32_16x16x32_bf16(kf, qf, (f32x4){0.f,0.f,0.f,0.f}, 0, 0, 0);
            const uchar4 rl4 = *(const uchar4*)&relrow[j0 + jg * 16 + g * 4];
            const u8* rl = (const u8*)&rl4;
            const float e0 = exp2f(fmaf(sc[0], rks2[rl[0]], rbs2[rl[0]]));
            const float e1 = exp2f(fmaf(sc[1], rks2[rl[1]], rbs2[rl[1]]));
            const float e2 = exp2f(fmaf(sc[2], rks2[rl[2]], rbs2[rl[2]]));
            const float e3 = exp2f(fmaf(sc[3], rks2[rl[3]], rbs2[rl[3]]));
            lrun += (e0 + e1) + (e2 + e3);
            ushort4 pb;
            pb.x = f2bf(e0); pb.y = f2bf(e1); pb.z = f2bf(e2); pb.w = f2bf(e3);
            *(ushort4*)&Pst[w][c * 72 + jg * 16 + g * 4] = pb;
        }
#pragma unroll
        for (int jc = 0; jc < 2; ++jc) {
            const short8 pf = *(const short8*)&Pst[w][c * 72 + jc * 32 + g * 8];
#pragma unroll
            for (int dg = 0; dg < 2; ++dg) {
                const short8 vf = *(const short8*)&Vt[buf][(dg * 16 + c) * 72 + jc * 32 + g * 8];
                Of[dg] = __builtin_amdgcn_mfma_f32_16x16x32_bf16(pf, vf, Of[dg], 0, 0, 0);
            }
        }

        if (t + 1 < NTI) {   // scatter the landed V(t+1); issue V(t+2)
            u16* vt = &Vt[buf ^ 1][0];
#pragma unroll
            for (int k = 0; k < 8; ++k) vt[(vd0 + k) * 72 + vj] = (u16)vnext[k];
            if (t + 2 < NTI)
                vnext = *(const short8*)(Vbase + (size_t)(j0 + 128) * DKc);
        }
        __syncthreads();
    }

    lrun += __shfl_xor(lrun, 16);
    lrun += __shfl_xor(lrun, 32);
    if (g == 0)
        Lpart[((size_t)z * BBc * HHc + bh) * SSc + iw + c] = lrun;

#pragma unroll
    for (int dg = 0; dg < 2; ++dg) {
#pragma unroll
        for (int r = 0; r < 4; ++r) {
            OPartB[(size_t)z * NRc * HDKc +
                   ((size_t)b * SSc + iw + g * 4 + r) * HDKc + h * DKc + dg * 16 + c] = f2bf(Of[dg][r]);
        }
    }
}

// ---------------- attention sum: recompute p for all 4 layers, write att f32 once -----
__global__ __launch_bounds__(256)
void attn_sum(const u16* __restrict__ QKhist, const u8* __restrict__ rel8,
              const float* __restrict__ relk, const float* __restrict__ relb,
              const float* __restrict__ Lpart, float* __restrict__ att)
{
    __shared__ float rks2[LLc][2 * MMc + 1], rbs2[LLc][2 * MMc + 1];

    const int tid = threadIdx.x;
    const int w = tid >> 6, lane = tid & 63;
    const int g = lane >> 4, c = lane & 15;
    const int bh = blockIdx.y, b = bh >> 3, h = bh & 7;
    const int z = blockIdx.z;
    const int iw = blockIdx.x * 64 + w * 16;

    if (tid < LLc * (2 * MMc + 1)) {
        const int l = tid / (2 * MMc + 1), t = tid - l * (2 * MMc + 1);
        rks2[l][t] = relk[(size_t)(l * (2 * MMc + 1) + t) * HHc + h] * LOG2E;
        rbs2[l][t] = relb[(size_t)(l * (2 * MMc + 1) + t) * HHc + h] * LOG2E;
    }
    __syncthreads();

    short8 qf[LLc];
    const u16* Kb[LLc];
    float ri[LLc];
#pragma unroll
    for (int l = 0; l < LLc; ++l) {
        const u16* Ql = QKhist + (size_t)l * 2 * NRc * HDKc;
        qf[l] = *(const short8*)(Ql + ((size_t)bh * SSc + iw + c) * DKc + g * 8);
        Kb[l] = Ql + (size_t)NRc * HDKc + (size_t)bh * SSc * DKc + g * 8;
        float ls = 0.f;
#pragma unroll
        for (int zz = 0; zz < ZSP; ++zz)
            ls += Lpart[(size_t)(l * ZSP + zz) * BHS + bh * SSc + iw + c];
        ri[l] = 0.25f / ls;
    }
    const u8* relrow = rel8 + ((size_t)b * SSc + iw + c) * SSc;
    float* arow = att + ((size_t)bh * SSc + iw + c) * SSc;

    const int jbeg = z * (SSc / ZSP), jend = jbeg + SSc / ZSP;
    for (int j0 = jbeg; j0 < jend; j0 += 64) {
#pragma unroll
        for (int jg = 0; jg < 4; ++jg) {
            const int jj = j0 + jg * 16 + g * 4;
            const uchar4 rl4 = *(const uchar4*)&relrow[jj];
            const u8* rl = (const u8*)&rl4;
            f32x4 sum = {0.f, 0.f, 0.f, 0.f};
#pragma unroll
            for (int l = 0; l < LLc; ++l) {
                const short8 kf = *(const short8*)(Kb[l] + (size_t)(j0 + jg * 16 + c) * DKc);
                f32x4 sc = __builtin_amdgcn_mfma_f32_16x16x32_bf16(kf, qf[l], (f32x4){0.f,0.f,0.f,0.f}, 0, 0, 0);
#pragma unroll
                for (int r = 0; r < 4; ++r)
                    sum[r] += exp2f(fmaf(sc[r], rks2[l][rl[r]], rbs2[l][rl[r]])) * ri[l];
            }
            __builtin_nontemporal_store(sum, (f32x4*)&arow[jj]);
        }
    }
}

extern "C" void kernel_launch(void* const* d_in, const int* in_sizes, int n_in,
                              void* d_out, int out_size, void* d_ws, size_t ws_size,
                              hipStream_t stream)
{
    const size_t NF = (size_t)NRc * FFc;            // 1,048,576
    float* outx = (float*)d_out;
    float* att  = outx + NF;

    const size_t baseFloats = 10 * NF + (size_t)LLc * ZSP * BHS + 32 * NRc;
    const size_t needed = baseFloats * sizeof(float);
    if (ws_size < needed) { fill_f32<<<dim3(4096), dim3(256), 0, stream>>>(outx, 1000.0f); return; }

    const float* x0   = (const float*)d_in[0];
    const int*   pos  = (const int*)d_in[2];
    const float* Wq   = (const float*)d_in[3];
    const float* bq   = (const float*)d_in[4];
    const float* Wk   = (const float*)d_in[5];
    const float* bk   = (const float*)d_in[6];
    const float* Wv   = (const float*)d_in[7];
    const float* bv   = (const float*)d_in[8];
    const float* Wo   = (const float*)d_in[9];
    const float* bo   = (const float*)d_in[10];
    const float* relk = (const float*)d_in[11];
    const float* relb = (const float*)d_in[12];
    const float* ln1g = (const float*)d_in[13];
    const float* ln1b = (const float*)d_in[14];
    const float* W1   = (const float*)d_in[15];
    const float* b1   = (const float*)d_in[16];
    const float* W2   = (const float*)d_in[17];
    const float* b2   = (const float*)d_in[18];
    const float* ln2g = (const float*)d_in[19];
    const float* ln2b = (const float*)d_in[20];

    float* ws = (float*)d_ws;
    float* slot0 = ws;                       // X / T2
    float* slot2 = ws + 1 * NF;              // Vbf (u16) / T1 (f32)
    u8*    rel8  = (u8*)(ws + 2 * NF);       // 2NF floats worth
    u16*   OPartB= (u16*)(ws + 4 * NF);      // 4 slabs x NF u16
    u16*   MD    = OPartB;
    float* Lpart = ws + 6 * NF;              // [L][ZSP][BHS]
    float* PartT1= Lpart + (size_t)LLc * ZSP * BHS;   // [NRc][8][2]
    float* PartX = PartT1 + 16 * NRc;        // [NRc][8][2]
    u16*   QKhist= (u16*)(PartX + 16 * NRc); // [L][2][NF] bf16

    u16* Vbf = (u16*)slot2;

    const dim3 blk(256);
    build_rel8<<<dim3(8192), blk, 0, stream>>>(pos, rel8);

    for (int l = 0; l < LLc; ++l) {
        u16* Qbf = QKhist + (size_t)l * 2 * NF;
        u16* Kbf = Qbf + NF;
        float* LpartL = Lpart + (size_t)l * ZSP * BHS;

        if (l == 0) {
            qkv_mfma<false><<<dim3(4, 64, 3), blk, 0, stream>>>(x0, nullptr, nullptr, nullptr,
                Wq, bq, Wk, bk, Wv, bv, Qbf, Kbf, Vbf);
        } else {
            qkv_mfma<true><<<dim3(4, 64, 3), blk, 0, stream>>>(slot0, PartX,
                ln2g + (l - 1) * FFc, ln2b + (l - 1) * FFc,
                Wq + (size_t)l * FFc * HDKc, bq + l * HDKc,
                Wk + (size_t)l * FFc * HDKc, bk + l * HDKc,
                Wv + (size_t)l * FFc * HDKc, bv + l * HDKc, Qbf, Kbf, Vbf);
        }

        attn_probs<<<dim3(SSc / 64, BBc * HHc, ZSP), blk, 0, stream>>>(
            Qbf, Kbf, Vbf, rel8,
            relk + l * (2 * MMc + 1) * HHc, relb + l * (2 * MMc + 1) * HHc, LpartL,
            OPartB);

        // T1 = (sum_z OPartB) / l_row @ Wo + bo -> slot2 (inline Lpart sum); PartT1 stats
        float* T1 = slot2;   // V dead
        gemm_mfma<0, ZSP, false, true, 2, true, true><<<dim3(HDKc / 32, 64), blk, 0, stream>>>(
            OPartB, (size_t)NRc * HDKc, nullptr, PartT1, nullptr, nullptr, LpartL,
            Wo + (size_t)l * HDKc * FFc, bo + l * FFc, T1, nullptr, FFc, HDKc);

        // MD(bf16) = GELU(LN1(T1) @ W1 + b1); LN1 stats from PartT1
        gemm_mfma<3, 1, true, false, 4, false, false><<<dim3(F4c / 64, 64), blk, 0, stream>>>(
            T1, 0, PartT1, nullptr, ln1g + l * FFc, ln1b + l * FFc, nullptr,
            W1 + (size_t)l * FFc * F4c, b1 + l * F4c, nullptr, MD, F4c, FFc);

        // T2 = MD @ W2 + b2 -> slot0; PartX stats (next layer's LN2)
        gemm_mfma<0, 1, false, true, 2, false, true><<<dim3(FFc / 32, 64), blk, 0, stream>>>(
            MD, 0, nullptr, PartX, nullptr, nullptr, nullptr,
            W2 + (size_t)l * F4c * FFc, b2 + l * FFc, slot0, nullptr, FFc, F4c);

        if (l == LLc - 1)
            ln_final<<<NRc / 4, blk, 0, stream>>>(slot0, ln2g + l * FFc, ln2b + l * FFc, outx);
    }

    // att = (sum_l p_l) / 4, recomputed from per-layer Q/K — written exactly once
    attn_sum<<<dim3(SSc / 64, BBc * HHc, ZSP), blk, 0, stream>>>(
        QKhist, rel8, relk, relb, Lpart, att);
}

// Round 20
// 640.338 us; speedup vs baseline: 1.0683x; 1.0683x over previous
//
#include <hip/hip_runtime.h>
#include <hip/hip_bf16.h>
#include <math.h>

#define LLc  4
#define BBc  2
#define SSc  2048
#define FFc  256
#define HHc  8
#define DKc  32
#define MMc  10
#define HDKc 256
#define F4c  1024
#define NRc  4096          /* B*S */
#define ISQD 0.17677669529663687f  /* 1/sqrt(32) */
#define LOG2E 1.4426950408889634f
#define ZSP  4             /* j-split */
#define BHS  32768         /* B*H*S */

typedef unsigned short u16;
typedef unsigned char  u8;
typedef unsigned int   u32;
typedef __attribute__((ext_vector_type(8))) short short8;
typedef __attribute__((ext_vector_type(4))) float f32x4;

__device__ __forceinline__ u16 f2bf(float f) {
    u32 x; __builtin_memcpy(&x, &f, 4);
    x += 0x7FFFu + ((x >> 16) & 1u);
    return (u16)(x >> 16);
}
__device__ __forceinline__ float bf2f(u16 u) {
    u32 x = ((u32)u) << 16; float f; __builtin_memcpy(&f, &x, 4); return f;
}

__global__ __launch_bounds__(256)
void fill_f32(float* __restrict__ p, float v) {
    p[(size_t)blockIdx.x * 256 + threadIdx.x] = v;
}

// ---------------- rel index table: rel8[b][i][j], u8, layer-invariant ----------------
__global__ __launch_bounds__(256)
void build_rel8(const int* __restrict__ pos, u8* __restrict__ rel8)
{
    const int id = blockIdx.x * 256 + threadIdx.x;      // B*S*S/4
    const int j4 = id & (SSc / 4 - 1);
    const int i  = (id >> 9) & (SSc - 1);
    const int b  = id >> 20;
    const int pi = pos[b * SSc + i];
    uchar4 o;
    u8* po = (u8*)&o;
#pragma unroll
    for (int t = 0; t < 4; ++t) {
        const int pj = pos[b * SSc + j4 * 4 + t];
        int dd = pi - pj; if (dd < 0) dd = -dd;
        int ridx = dd;
        if (dd > MMc) {
            int v = (int)(10.0f + __log2f((float)(dd - MMc)));
            ridx = v > 2 * MMc ? 2 * MMc : v;
        }
        po[t] = (u8)ridx;
    }
    *(uchar4*)&rel8[(size_t)id * 4] = o;
}

// ---------------- fused QKV GEMM: grid (4, 64, 3); z: 0=Q 1=K 2=V ---------------------
template<bool LNA>
__global__ __launch_bounds__(256)
void qkv_mfma(const float* __restrict__ A,
              const float* __restrict__ PartIn,
              const float* __restrict__ lng, const float* __restrict__ lnb,
              const float* __restrict__ Wq, const float* __restrict__ bq_,
              const float* __restrict__ Wk, const float* __restrict__ bk_,
              const float* __restrict__ Wv, const float* __restrict__ bv_,
              u16* __restrict__ Qbf, u16* __restrict__ Kbf, u16* __restrict__ Vbf)
{
    __shared__ u16 As[64][40];
    __shared__ u16 Bt[64][40];
    const int tid = threadIdx.x;
    const int w = tid >> 6, lane = tid & 63;
    const int g = lane >> 4, c = lane & 15;
    const int i0 = blockIdx.y * 64, n0 = blockIdx.x * 64;
    const int srow = tid & 63, sk8 = (tid >> 6) * 8;

    const float* W; const float* bias; u16* Out; float scale;
    if (blockIdx.z == 0)      { W = Wq; bias = bq_; Out = Qbf; scale = ISQD; }
    else if (blockIdx.z == 1) { W = Wk; bias = bk_; Out = Kbf; scale = 1.0f; }
    else                      { W = Wv; bias = bv_; Out = Vbf; scale = 1.0f; }

    float mu = 0.f, iv = 0.f;
    if (LNA) {
        const float* pp = PartIn + (size_t)(i0 + srow) * 16;
        float ls = 0.f, ss = 0.f;
#pragma unroll
        for (int t = 0; t < 8; ++t) { ls += pp[t * 2]; ss += pp[t * 2 + 1]; }
        mu = ls * (1.0f / FFc);
        float var = ss * (1.0f / FFc) - mu * mu;
        var = fmaxf(var, 0.0f);
        iv = 1.0f / sqrtf(var + 1e-5f);
    }

    f32x4 acc[4] = {{0.f,0.f,0.f,0.f},{0.f,0.f,0.f,0.f},{0.f,0.f,0.f,0.f},{0.f,0.f,0.f,0.f}};

    for (int k0 = 0; k0 < FFc; k0 += 32) {
        __syncthreads();
        {
            const float* ap = A + (size_t)(i0 + srow) * FFc + k0 + sk8;
            float v[8];
            *(float4*)&v[0] = *(const float4*)&ap[0];
            *(float4*)&v[4] = *(const float4*)&ap[4];
            if (LNA) {
#pragma unroll
                for (int t = 0; t < 8; ++t)
                    v[t] = (v[t] - mu) * iv * lng[k0 + sk8 + t] + lnb[k0 + sk8 + t];
            }
            short8 st;
#pragma unroll
            for (int t = 0; t < 8; ++t) st[t] = (short)f2bf(v[t]);
            *(short8*)&As[srow][sk8] = st;
        }
        {
            const float* wp = W + (size_t)(k0 + sk8) * HDKc + n0 + srow;
            short8 st;
#pragma unroll
            for (int t = 0; t < 8; ++t) st[t] = (short)f2bf(wp[(size_t)t * HDKc]);
            *(short8*)&Bt[srow][sk8] = st;
        }
        __syncthreads();
        const short8 af = *(const short8*)&As[w * 16 + c][g * 8];
#pragma unroll
        for (int nt = 0; nt < 4; ++nt) {
            const short8 bf = *(const short8*)&Bt[nt * 16 + c][g * 8];
            acc[nt] = __builtin_amdgcn_mfma_f32_16x16x32_bf16(af, bf, acc[nt], 0, 0, 0);
        }
    }

#pragma unroll
    for (int nt = 0; nt < 4; ++nt) {
        const int col = n0 + nt * 16 + c;
        const float bsv = bias[col];
#pragma unroll
        for (int r = 0; r < 4; ++r) {
            const int row = i0 + w * 16 + g * 4 + r;
            const int b = row >> 11, s = row & (SSc - 1);
            const int h = col >> 5, d = col & 31;
            Out[((size_t)(b * HHc + h) * SSc + s) * DKc + d] = f2bf((acc[nt][r] + bsv) * scale);
        }
    }
}

// ---------------- generic bf16-MFMA GEMM -----------------------------------------------
// MODE 0: f32 out. MODE 3: GELU -> bf16 out. NSUM slabs summed. LNA: LN on A (f32 A),
// stats from PartIn. ABF: A bf16. LSC: scale A by 1/sum_z Lpart (inline). EMITPS: emit
// per-block row partial (sum, sumsq) into PartOut[row][8][2] (NT==2 producers only).
template<int MODE, int NSUM, bool LNA, bool ABF, int NT, bool LSC, bool EMITPS>
__global__ __launch_bounds__(256)
void gemm_mfma(const void* __restrict__ Aptr, size_t Astride,
               const float* __restrict__ PartIn, float* __restrict__ PartOut,
               const float* __restrict__ lng, const float* __restrict__ lnb,
               const float* __restrict__ Lpart,
               const float* __restrict__ W, const float* __restrict__ bias,
               float* __restrict__ C, u16* __restrict__ Cb, int Nc, int Kd)
{
    __shared__ u16 As[64][40];
    __shared__ u16 Bt[NT * 16][40];
    const int tid = threadIdx.x;
    const int w = tid >> 6, lane = tid & 63;
    const int g = lane >> 4, c = lane & 15;
    const int i0 = blockIdx.y * 64, n0 = blockIdx.x * (NT * 16);
    const int srow = tid & 63, sk8 = (tid >> 6) * 8;

    float mu = 0.f, iv = 0.f;
    if (LNA) {
        const float* pp = PartIn + (size_t)(i0 + srow) * 16;
        float ls = 0.f, ss = 0.f;
#pragma unroll
        for (int t = 0; t < 8; ++t) { ls += pp[t * 2]; ss += pp[t * 2 + 1]; }
        mu = ls * (1.0f / FFc);
        float var = ss * (1.0f / FFc) - mu * mu;
        var = fmaxf(var, 0.0f);
        iv = 1.0f / sqrtf(var + 1e-5f);
    }

    f32x4 acc[NT];
#pragma unroll
    for (int nt = 0; nt < NT; ++nt) acc[nt] = (f32x4){0.f, 0.f, 0.f, 0.f};

    for (int k0 = 0; k0 < Kd; k0 += 32) {
        __syncthreads();
        if (ABF) {
            const u16* ap = (const u16*)Aptr + (size_t)(i0 + srow) * Kd + k0 + sk8;
            if (NSUM == 1 && !LSC) {
                *(short8*)&As[srow][sk8] = *(const short8*)ap;
            } else {
                float v[8];
                const short8 s0 = *(const short8*)ap;
#pragma unroll
                for (int e = 0; e < 8; ++e) v[e] = bf2f((u16)s0[e]);
#pragma unroll
                for (int t = 1; t < NSUM; ++t) {
                    const short8 st = *(const short8*)(ap + (size_t)t * Astride);
#pragma unroll
                    for (int e = 0; e < 8; ++e) v[e] += bf2f((u16)st[e]);
                }
                if (LSC) {
                    const int row = i0 + srow;
                    const int h = (k0 + sk8) >> 5;
                    const int bhs = (((row >> 11) * HHc + h) * SSc) + (row & (SSc - 1));
                    float ls = 0.f;
#pragma unroll
                    for (int z = 0; z < ZSP; ++z) ls += Lpart[(size_t)z * BHS + bhs];
                    const float scl = 1.0f / ls;
#pragma unroll
                    for (int e = 0; e < 8; ++e) v[e] *= scl;
                }
                short8 so;
#pragma unroll
                for (int e = 0; e < 8; ++e) so[e] = (short)f2bf(v[e]);
                *(short8*)&As[srow][sk8] = so;
            }
        } else {
            const float* ap = (const float*)Aptr + (size_t)(i0 + srow) * Kd + k0 + sk8;
            float v[8];
            *(float4*)&v[0] = *(const float4*)&ap[0];
            *(float4*)&v[4] = *(const float4*)&ap[4];
            if (LNA) {
#pragma unroll
                for (int t = 0; t < 8; ++t)
                    v[t] = (v[t] - mu) * iv * lng[k0 + sk8 + t] + lnb[k0 + sk8 + t];
            }
            short8 st;
#pragma unroll
            for (int t = 0; t < 8; ++t) st[t] = (short)f2bf(v[t]);
            *(short8*)&As[srow][sk8] = st;
        }
        if (NT == 4) {
            const float* wp = W + (size_t)(k0 + sk8) * Nc + n0 + srow;
            short8 st;
#pragma unroll
            for (int t = 0; t < 8; ++t) st[t] = (short)f2bf(wp[(size_t)t * Nc]);
            *(short8*)&Bt[srow][sk8] = st;
        } else {  // NT == 2: 32 cols x 32 k, 4 elems/thread
            const int col = tid & 31, kb = (tid >> 5) * 4;
            const float* wp = W + (size_t)(k0 + kb) * Nc + n0 + col;
            ushort4 st;
            st.x = f2bf(wp[0]);
            st.y = f2bf(wp[(size_t)1 * Nc]);
            st.z = f2bf(wp[(size_t)2 * Nc]);
            st.w = f2bf(wp[(size_t)3 * Nc]);
            *(ushort4*)&Bt[col][kb] = st;
        }
        __syncthreads();
        const short8 af = *(const short8*)&As[w * 16 + c][g * 8];
#pragma unroll
        for (int nt = 0; nt < NT; ++nt) {
            const short8 bf = *(const short8*)&Bt[nt * 16 + c][g * 8];
            acc[nt] = __builtin_amdgcn_mfma_f32_16x16x32_bf16(af, bf, acc[nt], 0, 0, 0);
        }
    }

    float vv[NT][4];
#pragma unroll
    for (int nt = 0; nt < NT; ++nt) {
        const int col = n0 + nt * 16 + c;
        const float bsv = bias[col];
#pragma unroll
        for (int r = 0; r < 4; ++r) {
            float v = acc[nt][r] + bsv;
            vv[nt][r] = v;
            const int row = i0 + w * 16 + g * 4 + r;
            if (MODE == 3) {
                const float ge = 0.5f * v * (1.0f + erff(v * 0.70710678118654752f));
                Cb[(size_t)row * Nc + col] = f2bf(ge);
            } else {
                C[(size_t)row * Nc + col] = v;
            }
        }
    }
    if (EMITPS) {
#pragma unroll
        for (int r = 0; r < 4; ++r) {
            float s  = vv[0][r] + vv[1][r];
            float s2 = vv[0][r] * vv[0][r] + vv[1][r] * vv[1][r];
#pragma unroll
            for (int m = 1; m < 16; m <<= 1) { s += __shfl_xor(s, m, 16); s2 += __shfl_xor(s2, m, 16); }
            if (c == 0) {
                const int row = i0 + w * 16 + g * 4 + r;
                PartOut[(size_t)row * 16 + blockIdx.x * 2]     = s;
                PartOut[(size_t)row * 16 + blockIdx.x * 2 + 1] = s2;
            }
        }
    }
}

// ---------------- final LayerNorm -> f32 d_out x region -------------------------------
__global__ __launch_bounds__(256)
void ln_final(const float* __restrict__ Xi, const float* __restrict__ g,
              const float* __restrict__ bia, float* __restrict__ Yout)
{
    const int row = blockIdx.x * 4 + (threadIdx.x >> 6);
    const int lane = threadIdx.x & 63;
    const float4 v = *(const float4*)&Xi[(size_t)row * FFc + lane * 4];
    float s = v.x + v.y + v.z + v.w;
    float s2 = v.x * v.x + v.y * v.y + v.z * v.z + v.w * v.w;
#pragma unroll
    for (int m = 1; m < 64; m <<= 1) { s += __shfl_xor(s, m); s2 += __shfl_xor(s2, m); }
    const float mu = s * (1.0f / FFc);
    float var = s2 * (1.0f / FFc) - mu * mu;
    var = fmaxf(var, 0.0f);
    const float inv = 1.0f / sqrtf(var + 1e-5f);
    const float4 gv = *(const float4*)&g[lane * 4];
    const float4 bv = *(const float4*)&bia[lane * 4];
    float4 o;
    o.x = (v.x - mu) * inv * gv.x + bv.x;
    o.y = (v.y - mu) * inv * gv.y + bv.y;
    o.z = (v.z - mu) * inv * gv.z + bv.z;
    o.w = (v.w - mu) * inv * gv.w + bv.w;
    *(float4*)&Yout[(size_t)row * FFc + lane * 4] = o;
}

// ---------------- attention probs: UNNORMALIZED p -> PV; emits Lpart (R18 structure) --
__global__ __launch_bounds__(256)
void attn_probs(const u16* __restrict__ Qbf, const u16* __restrict__ Kbf,
                const u16* __restrict__ Vbf,
                const u8* __restrict__ rel8,
                const float* __restrict__ rk_t, const float* __restrict__ rb_t,
                float* __restrict__ Lpart,
                u16* __restrict__ OPartB)
{
    __shared__ u16 Vt[32 * 72];
    __shared__ u16 Pst[4][16 * 72];
    __shared__ float rks2[2 * MMc + 1], rbs2[2 * MMc + 1];

    const int tid = threadIdx.x;
    const int w = tid >> 6, lane = tid & 63;
    const int g = lane >> 4, c = lane & 15;
    const int bh = blockIdx.y, b = bh >> 3, h = bh & 7;
    const int z = blockIdx.z;
    const int iw = blockIdx.x * 64 + w * 16;

    if (tid < 2 * MMc + 1) {
        rks2[tid] = rk_t[tid * HHc + h] * LOG2E;
        rbs2[tid] = rb_t[tid * HHc + h] * LOG2E;
    }
    const short8 qf = *(const short8*)(Qbf + ((size_t)bh * SSc + iw + c) * DKc + g * 8);
    const u8* relrow = rel8 + ((size_t)b * SSc + iw + c) * SSc;
    const u16* Kbase = Kbf + (size_t)bh * SSc * DKc + g * 8;

    float lrun = 0.f;
    f32x4 Of[2] = {{0.f,0.f,0.f,0.f}, {0.f,0.f,0.f,0.f}};
    const int jbeg = z * (SSc / ZSP), jend = jbeg + SSc / ZSP;
    for (int j0 = jbeg; j0 < jend; j0 += 64) {
        __syncthreads();
        {
            const int j = tid >> 2, seg = tid & 3;
            const short8 vvv = *(const short8*)(Vbf + ((size_t)bh * SSc + j0 + j) * DKc + seg * 8);
            const int d0 = seg * 8;
#pragma unroll
            for (int k = 0; k < 8; ++k) Vt[(d0 + k) * 72 + j] = (u16)vvv[k];
        }
        __syncthreads();

#pragma unroll
        for (int jg = 0; jg < 4; ++jg) {
            const short8 kf = *(const short8*)(Kbase + (size_t)(j0 + jg * 16 + c) * DKc);
            f32x4 sc = __builtin_amdgcn_mfma_f32_16x16x32_bf16(kf, qf, (f32x4){0.f,0.f,0.f,0.f}, 0, 0, 0);
            const uchar4 rl4 = *(const uchar4*)&relrow[j0 + jg * 16 + g * 4];
            const u8* rl = (const u8*)&rl4;
            const float e0 = exp2f(fmaf(sc[0], rks2[rl[0]], rbs2[rl[0]]));
            const float e1 = exp2f(fmaf(sc[1], rks2[rl[1]], rbs2[rl[1]]));
            const float e2 = exp2f(fmaf(sc[2], rks2[rl[2]], rbs2[rl[2]]));
            const float e3 = exp2f(fmaf(sc[3], rks2[rl[3]], rbs2[rl[3]]));
            lrun += (e0 + e1) + (e2 + e3);
            ushort4 pb;
            pb.x = f2bf(e0); pb.y = f2bf(e1); pb.z = f2bf(e2); pb.w = f2bf(e3);
            *(ushort4*)&Pst[w][c * 72 + jg * 16 + g * 4] = pb;
        }
#pragma unroll
        for (int jc = 0; jc < 2; ++jc) {
            const short8 pf = *(const short8*)&Pst[w][c * 72 + jc * 32 + g * 8];
#pragma unroll
            for (int dg = 0; dg < 2; ++dg) {
                const short8 vf = *(const short8*)&Vt[(dg * 16 + c) * 72 + jc * 32 + g * 8];
                Of[dg] = __builtin_amdgcn_mfma_f32_16x16x32_bf16(pf, vf, Of[dg], 0, 0, 0);
            }
        }
    }

    lrun += __shfl_xor(lrun, 16);
    lrun += __shfl_xor(lrun, 32);
    if (g == 0)
        Lpart[((size_t)z * BBc * HHc + bh) * SSc + iw + c] = lrun;

#pragma unroll
    for (int dg = 0; dg < 2; ++dg) {
#pragma unroll
        for (int r = 0; r < 4; ++r) {
            OPartB[(size_t)z * NRc * HDKc +
                   ((size_t)b * SSc + iw + g * 4 + r) * HDKc + h * DKc + dg * 16 + c] = f2bf(Of[dg][r]);
        }
    }
}

// ---------------- attention sum: recompute p for all 4 layers, write att f32 once -----
__global__ __launch_bounds__(256)
void attn_sum(const u16* __restrict__ QKhist, const u8* __restrict__ rel8,
              const float* __restrict__ relk, const float* __restrict__ relb,
              const float* __restrict__ Lpart, float* __restrict__ att)
{
    __shared__ float rks2[LLc][2 * MMc + 1], rbs2[LLc][2 * MMc + 1];

    const int tid = threadIdx.x;
    const int w = tid >> 6, lane = tid & 63;
    const int g = lane >> 4, c = lane & 15;
    const int bh = blockIdx.y, b = bh >> 3, h = bh & 7;
    const int z = blockIdx.z;
    const int iw = blockIdx.x * 64 + w * 16;

    if (tid < LLc * (2 * MMc + 1)) {
        const int l = tid / (2 * MMc + 1), t = tid - l * (2 * MMc + 1);
        rks2[l][t] = relk[(size_t)(l * (2 * MMc + 1) + t) * HHc + h] * LOG2E;
        rbs2[l][t] = relb[(size_t)(l * (2 * MMc + 1) + t) * HHc + h] * LOG2E;
    }
    __syncthreads();

    short8 qf[LLc];
    const u16* Kb[LLc];
    float ri[LLc];
#pragma unroll
    for (int l = 0; l < LLc; ++l) {
        const u16* Ql = QKhist + (size_t)l * 2 * NRc * HDKc;
        qf[l] = *(const short8*)(Ql + ((size_t)bh * SSc + iw + c) * DKc + g * 8);
        Kb[l] = Ql + (size_t)NRc * HDKc + (size_t)bh * SSc * DKc + g * 8;
        float ls = 0.f;
#pragma unroll
        for (int zz = 0; zz < ZSP; ++zz)
            ls += Lpart[(size_t)(l * ZSP + zz) * BHS + bh * SSc + iw + c];
        ri[l] = 0.25f / ls;
    }
    const u8* relrow = rel8 + ((size_t)b * SSc + iw + c) * SSc;
    float* arow = att + ((size_t)bh * SSc + iw + c) * SSc;

    const int jbeg = z * (SSc / ZSP), jend = jbeg + SSc / ZSP;
    for (int j0 = jbeg; j0 < jend; j0 += 64) {
#pragma unroll
        for (int jg = 0; jg < 4; ++jg) {
            const int jj = j0 + jg * 16 + g * 4;
            const uchar4 rl4 = *(const uchar4*)&relrow[jj];
            const u8* rl = (const u8*)&rl4;
            f32x4 sum = {0.f, 0.f, 0.f, 0.f};
#pragma unroll
            for (int l = 0; l < LLc; ++l) {
                const short8 kf = *(const short8*)(Kb[l] + (size_t)(j0 + jg * 16 + c) * DKc);
                f32x4 sc = __builtin_amdgcn_mfma_f32_16x16x32_bf16(kf, qf[l], (f32x4){0.f,0.f,0.f,0.f}, 0, 0, 0);
#pragma unroll
                for (int r = 0; r < 4; ++r)
                    sum[r] += exp2f(fmaf(sc[r], rks2[l][rl[r]], rbs2[l][rl[r]])) * ri[l];
            }
            __builtin_nontemporal_store(sum, (f32x4*)&arow[jj]);
        }
    }
}

extern "C" void kernel_launch(void* const* d_in, const int* in_sizes, int n_in,
                              void* d_out, int out_size, void* d_ws, size_t ws_size,
                              hipStream_t stream)
{
    const size_t NF = (size_t)NRc * FFc;            // 1,048,576
    float* outx = (float*)d_out;
    float* att  = outx + NF;

    const size_t baseFloats = 10 * NF + (size_t)LLc * ZSP * BHS + 32 * NRc;
    const size_t needed = baseFloats * sizeof(float);
    if (ws_size < needed) { fill_f32<<<dim3(4096), dim3(256), 0, stream>>>(outx, 1000.0f); return; }

    const float* x0   = (const float*)d_in[0];
    const int*   pos  = (const int*)d_in[2];
    const float* Wq   = (const float*)d_in[3];
    const float* bq   = (const float*)d_in[4];
    const float* Wk   = (const float*)d_in[5];
    const float* bk   = (const float*)d_in[6];
    const float* Wv   = (const float*)d_in[7];
    const float* bv   = (const float*)d_in[8];
    const float* Wo   = (const float*)d_in[9];
    const float* bo   = (const float*)d_in[10];
    const float* relk = (const float*)d_in[11];
    const float* relb = (const float*)d_in[12];
    const float* ln1g = (const float*)d_in[13];
    const float* ln1b = (const float*)d_in[14];
    const float* W1   = (const float*)d_in[15];
    const float* b1   = (const float*)d_in[16];
    const float* W2   = (const float*)d_in[17];
    const float* b2   = (const float*)d_in[18];
    const float* ln2g = (const float*)d_in[19];
    const float* ln2b = (const float*)d_in[20];

    float* ws = (float*)d_ws;
    float* slot0 = ws;                       // X / T2
    float* slot2 = ws + 1 * NF;              // Vbf (u16) / T1 (f32)
    u8*    rel8  = (u8*)(ws + 2 * NF);       // 2NF floats worth
    u16*   OPartB= (u16*)(ws + 4 * NF);      // 4 slabs x NF u16
    u16*   MD    = OPartB;
    float* Lpart = ws + 6 * NF;              // [L][ZSP][BHS]
    float* PartT1= Lpart + (size_t)LLc * ZSP * BHS;   // [NRc][8][2]
    float* PartX = PartT1 + 16 * NRc;        // [NRc][8][2]
    u16*   QKhist= (u16*)(PartX + 16 * NRc); // [L][2][NF] bf16

    u16* Vbf = (u16*)slot2;

    const dim3 blk(256);
    build_rel8<<<dim3(8192), blk, 0, stream>>>(pos, rel8);

    for (int l = 0; l < LLc; ++l) {
        u16* Qbf = QKhist + (size_t)l * 2 * NF;
        u16* Kbf = Qbf + NF;
        float* LpartL = Lpart + (size_t)l * ZSP * BHS;

        if (l == 0) {
            qkv_mfma<false><<<dim3(4, 64, 3), blk, 0, stream>>>(x0, nullptr, nullptr, nullptr,
                Wq, bq, Wk, bk, Wv, bv, Qbf, Kbf, Vbf);
        } else {
            qkv_mfma<true><<<dim3(4, 64, 3), blk, 0, stream>>>(slot0, PartX,
                ln2g + (l - 1) * FFc, ln2b + (l - 1) * FFc,
                Wq + (size_t)l * FFc * HDKc, bq + l * HDKc,
                Wk + (size_t)l * FFc * HDKc, bk + l * HDKc,
                Wv + (size_t)l * FFc * HDKc, bv + l * HDKc, Qbf, Kbf, Vbf);
        }

        attn_probs<<<dim3(SSc / 64, BBc * HHc, ZSP), blk, 0, stream>>>(
            Qbf, Kbf, Vbf, rel8,
            relk + l * (2 * MMc + 1) * HHc, relb + l * (2 * MMc + 1) * HHc, LpartL,
            OPartB);

        // T1 = (sum_z OPartB) / l_row @ Wo + bo -> slot2 (inline Lpart sum); PartT1 stats
        float* T1 = slot2;   // V dead
        gemm_mfma<0, ZSP, false, true, 2, true, true><<<dim3(HDKc / 32, 64), blk, 0, stream>>>(
            OPartB, (size_t)NRc * HDKc, nullptr, PartT1, nullptr, nullptr, LpartL,
            Wo + (size_t)l * HDKc * FFc, bo + l * FFc, T1, nullptr, FFc, HDKc);

        // MD(bf16) = GELU(LN1(T1) @ W1 + b1); LN1 stats from PartT1
        gemm_mfma<3, 1, true, false, 4, false, false><<<dim3(F4c / 64, 64), blk, 0, stream>>>(
            T1, 0, PartT1, nullptr, ln1g + l * FFc, ln1b + l * FFc, nullptr,
            W1 + (size_t)l * FFc * F4c, b1 + l * F4c, nullptr, MD, F4c, FFc);

        // T2 = MD @ W2 + b2 -> slot0; PartX stats (next layer's LN2)
        gemm_mfma<0, 1, false, true, 2, false, true><<<dim3(FFc / 32, 64), blk, 0, stream>>>(
            MD, 0, nullptr, PartX, nullptr, nullptr, nullptr,
            W2 + (size_t)l * F4c * FFc, b2 + l * FFc, slot0, nullptr, FFc, F4c);

        if (l == LLc - 1)
            ln_final<<<NRc / 4, blk, 0, stream>>>(slot0, ln2g + l * FFc, ln2b + l * FFc, outx);
    }

    // att = (sum_l p_l) / 4, recomputed from per-layer Q/K — written exactly once
    attn_sum<<<dim3(SSc / 64, BBc * HHc, ZSP), blk, 0, stream>>>(
        QKhist, rel8, relk, relb, Lpart, att);
}